// Round 1
// baseline (9271.061 us; speedup 1.0000x reference)
//
#include <hip/hip_runtime.h>

#define NFEAT 300
#define F4 75      // float4 chunks per 300-float row
#define NGRAPH 2048

// ---------------------------------------------------------------------------
// aggr[v] = h[v] + emb1[0] + emb2[0]   (self-loop with zero edge_attr)
// ---------------------------------------------------------------------------
__global__ __launch_bounds__(256) void k_init_aggr(
    const float* __restrict__ h, const float* __restrict__ emb1,
    const float* __restrict__ emb2, float* __restrict__ A, int n)
{
    int idx = blockIdx.x * blockDim.x + threadIdx.x;
    if (idx >= n * F4) return;
    int v = idx / F4, c = idx % F4;
    float4 hv = ((const float4*)h)[v * F4 + c];
    float4 e1 = ((const float4*)emb1)[c];   // row 0 of emb1
    float4 e2 = ((const float4*)emb2)[c];   // row 0 of emb2
    float4 r;
    r.x = hv.x + e1.x + e2.x;
    r.y = hv.y + e1.y + e2.y;
    r.z = hv.z + e1.z + e2.z;
    r.w = hv.w + e1.w + e2.w;
    ((float4*)A)[v * F4 + c] = r;
}

// ---------------------------------------------------------------------------
// For each real edge e: aggr[dst[e]] += h[src[e]] + emb1[type] + emb2[dir]
// One thread per (edge, float4 chunk).
// ---------------------------------------------------------------------------
__global__ __launch_bounds__(256) void k_scatter(
    const float* __restrict__ h, const int* __restrict__ ei,
    const int* __restrict__ ea, const float* __restrict__ emb1,
    const float* __restrict__ emb2, float* __restrict__ A, int E)
{
    int idx = blockIdx.x * blockDim.x + threadIdx.x;
    if (idx >= E * F4) return;
    int e = idx / F4, c = idx % F4;
    int s = ei[e];          // src
    int v = ei[E + e];      // dst
    int t = ea[2 * e];      // bond type  -> emb1
    int d = ea[2 * e + 1];  // bond dir   -> emb2
    float4 hv = ((const float4*)h)[s * F4 + c];
    float4 e1 = ((const float4*)emb1)[t * F4 + c];
    float4 e2 = ((const float4*)emb2)[d * F4 + c];
    float m0 = hv.x + e1.x + e2.x;
    float m1 = hv.y + e1.y + e2.y;
    float m2 = hv.z + e1.z + e2.z;
    float m3 = hv.w + e1.w + e2.w;
    float* p = A + (size_t)v * NFEAT + 4 * c;
    __hip_atomic_fetch_add(p + 0, m0, __ATOMIC_RELAXED, __HIP_MEMORY_SCOPE_AGENT);
    __hip_atomic_fetch_add(p + 1, m1, __ATOMIC_RELAXED, __HIP_MEMORY_SCOPE_AGENT);
    __hip_atomic_fetch_add(p + 2, m2, __ATOMIC_RELAXED, __HIP_MEMORY_SCOPE_AGENT);
    __hip_atomic_fetch_add(p + 3, m3, __ATOMIC_RELAXED, __HIP_MEMORY_SCOPE_AGENT);
}

// ---------------------------------------------------------------------------
// Fused MLP: Hout = relu( relu(A @ W1 + b1) @ W2 + b2 )
// 16 rows per block; intermediate 16x600 tile lives in LDS (57.6 KB total).
// Thread layout: 8 groups (ty) x 32 lanes (tx); each thread owns 2 rows.
// ---------------------------------------------------------------------------
__global__ __launch_bounds__(256) void k_mlp(
    const float* __restrict__ A, const float* __restrict__ W1,
    const float* __restrict__ b1, const float* __restrict__ W2,
    const float* __restrict__ b2, float* __restrict__ Hout, int nrows)
{
    __shared__ float sA[16 * NFEAT];   // 19.2 KB
    __shared__ float sT[16 * 600];     // 38.4 KB
    int tid = threadIdx.x;
    int r0 = blockIdx.x * 16;

    // stage A tile
    for (int i = tid; i < 16 * F4; i += 256) {
        int r = i / F4, c = i % F4;
        int gr = r0 + r;
        float4 v = (gr < nrows) ? ((const float4*)A)[gr * F4 + c]
                                : make_float4(0.f, 0.f, 0.f, 0.f);
        ((float4*)sA)[r * F4 + c] = v;
    }
    __syncthreads();

    int ty = tid >> 5;   // 0..7 -> rows 2*ty, 2*ty+1
    int tx = tid & 31;

    // ---- phase 1: T = relu(A @ W1 + b1), T is 16 x 600 ----
    float acc[2][19];
#pragma unroll
    for (int j = 0; j < 19; ++j) {
        int c = tx + 32 * j;
        float bv = (c < 600) ? b1[c] : 0.f;
        acc[0][j] = bv;
        acc[1][j] = bv;
    }
    for (int k = 0; k < NFEAT; ++k) {
        float a0 = sA[(2 * ty + 0) * NFEAT + k];
        float a1 = sA[(2 * ty + 1) * NFEAT + k];
        const float* wrow = W1 + (size_t)k * 600;
#pragma unroll
        for (int j = 0; j < 19; ++j) {
            int c = tx + 32 * j;
            if (c < 600) {
                float w = wrow[c];
                acc[0][j] = fmaf(a0, w, acc[0][j]);
                acc[1][j] = fmaf(a1, w, acc[1][j]);
            }
        }
    }
#pragma unroll
    for (int j = 0; j < 19; ++j) {
        int c = tx + 32 * j;
        if (c < 600) {
            sT[(2 * ty + 0) * 600 + c] = fmaxf(acc[0][j], 0.f);
            sT[(2 * ty + 1) * 600 + c] = fmaxf(acc[1][j], 0.f);
        }
    }
    __syncthreads();

    // ---- phase 2: H = relu(T @ W2 + b2), H is 16 x 300 ----
    float acc2[2][10];
#pragma unroll
    for (int j = 0; j < 10; ++j) {
        int c = tx + 32 * j;
        float bv = (c < NFEAT) ? b2[c] : 0.f;
        acc2[0][j] = bv;
        acc2[1][j] = bv;
    }
    for (int k = 0; k < 600; ++k) {
        float a0 = sT[(2 * ty + 0) * 600 + k];
        float a1 = sT[(2 * ty + 1) * 600 + k];
        const float* wrow = W2 + (size_t)k * NFEAT;
#pragma unroll
        for (int j = 0; j < 10; ++j) {
            int c = tx + 32 * j;
            if (c < NFEAT) {
                float w = wrow[c];
                acc2[0][j] = fmaf(a0, w, acc2[0][j]);
                acc2[1][j] = fmaf(a1, w, acc2[1][j]);
            }
        }
    }
#pragma unroll
    for (int j = 0; j < 10; ++j) {
        int c = tx + 32 * j;
        if (c < NFEAT) {
            int gr0 = r0 + 2 * ty;
            if (gr0 < nrows)     Hout[(size_t)gr0 * NFEAT + c]       = fmaxf(acc2[0][j], 0.f);
            if (gr0 + 1 < nrows) Hout[(size_t)(gr0 + 1) * NFEAT + c] = fmaxf(acc2[1][j], 0.f);
        }
    }
}

// ---------------------------------------------------------------------------
// Global add-pool: g[gid] = sum of H rows whose batch == gid. batch is sorted,
// so each block binary-searches its [start,end) range. No atomics.
// ---------------------------------------------------------------------------
__global__ __launch_bounds__(256) void k_pool(
    const float* __restrict__ H, const int* __restrict__ batch,
    float* __restrict__ g, int n)
{
    int gid = blockIdx.x;
    int lo = 0, hi = n;
    while (lo < hi) { int mid = (lo + hi) >> 1; if (batch[mid] < gid) lo = mid + 1; else hi = mid; }
    int start = lo;
    hi = n;
    while (lo < hi) { int mid = (lo + hi) >> 1; if (batch[mid] < gid + 1) lo = mid + 1; else hi = mid; }
    int end = lo;

    for (int f = threadIdx.x; f < NFEAT; f += blockDim.x) {
        float acc = 0.f;
        for (int v = start; v < end; ++v) acc += H[(size_t)v * NFEAT + f];
        g[(size_t)gid * NFEAT + f] = acc;
    }
}

// ---------------------------------------------------------------------------
// out = g @ Wfc + bfc   (2048x300 @ 300x300)
// ---------------------------------------------------------------------------
__global__ __launch_bounds__(256) void k_final(
    const float* __restrict__ g, const float* __restrict__ Wfc,
    const float* __restrict__ bfc, float* __restrict__ out)
{
    int idx = blockIdx.x * blockDim.x + threadIdx.x;
    if (idx >= NGRAPH * NFEAT) return;
    int r = idx / NFEAT, c = idx % NFEAT;
    float acc = bfc[c];
    for (int k = 0; k < NFEAT; ++k)
        acc = fmaf(g[(size_t)r * NFEAT + k], Wfc[(size_t)k * NFEAT + c], acc);
    out[idx] = acc;
}

extern "C" void kernel_launch(void* const* d_in, const int* in_sizes, int n_in,
                              void* d_out, int out_size, void* d_ws, size_t ws_size,
                              hipStream_t stream)
{
    const float* x    = (const float*)d_in[0];
    const int*   ei   = (const int*)  d_in[1];   // [2, E]
    const int*   ea   = (const int*)  d_in[2];   // [E, 2]
    const int*   batch= (const int*)  d_in[3];   // [N] sorted
    const float* emb1 = (const float*)d_in[4];
    const float* emb2 = (const float*)d_in[5];
    const float* W1   = (const float*)d_in[6];
    const float* b1   = (const float*)d_in[7];
    const float* W2   = (const float*)d_in[8];
    const float* b2   = (const float*)d_in[9];
    const float* Wfc  = (const float*)d_in[10];
    const float* bfc  = (const float*)d_in[11];
    float* out = (float*)d_out;

    int n = in_sizes[0] / NFEAT;   // 100000
    int E = in_sizes[1] / 2;       // 200000

    float* A  = (float*)d_ws;                  // n*300 floats (aggr)
    float* Hh = A + (size_t)n * NFEAT;         // n*300 floats (hidden)
    float* g  = Hh + (size_t)n * NFEAT;        // 2048*300 floats (pooled)

    dim3 blk(256);
    int initBlocks = (n * F4 + 255) / 256;
    int scatBlocks = (E * F4 + 255) / 256;
    int mlpBlocks  = (n + 15) / 16;

    // ---- layer 1: h = relu(mlp(scatter(x))) ----
    k_init_aggr<<<initBlocks, blk, 0, stream>>>(x, emb1, emb2, A, n);
    k_scatter  <<<scatBlocks, blk, 0, stream>>>(x, ei, ea, emb1, emb2, A, E);
    k_mlp      <<<mlpBlocks,  blk, 0, stream>>>(A, W1, b1, W2, b2, Hh, n);

    // ---- layer 2 ----
    k_init_aggr<<<initBlocks, blk, 0, stream>>>(Hh, emb1, emb2, A, n);
    k_scatter  <<<scatBlocks, blk, 0, stream>>>(Hh, ei, ea, emb1, emb2, A, E);
    k_mlp      <<<mlpBlocks,  blk, 0, stream>>>(A, W1, b1, W2, b2, Hh, n);

    // ---- pool + final FC ----
    k_pool <<<NGRAPH, blk, 0, stream>>>(Hh, batch, g, n);
    k_final<<<(NGRAPH * NFEAT + 255) / 256, blk, 0, stream>>>(g, Wfc, bfc, out);
}

// Round 2
// 2656.091 us; speedup vs baseline: 3.4905x; 3.4905x over previous
//
#include <hip/hip_runtime.h>
#include <hip/hip_bf16.h>

#define NFEAT 300
#define F4 75            // float4 chunks per 300-float row
#define NGRAPH 2048
#define K1P 320          // padded K for GEMM1 (300 -> 320)
#define N1P 640          // padded N for GEMM1 (600 -> 640)
#define K2P 640          // padded K for GEMM2
#define N2P 384          // padded N for GEMM2 (300 -> 384, 3 tiles of 128)

typedef __bf16 bf16x8 __attribute__((ext_vector_type(8)));
typedef float  f32x4  __attribute__((ext_vector_type(4)));

__device__ __forceinline__ unsigned short f2b(float v) {
    union { float f; unsigned u; } x; x.f = v;
    unsigned r = x.u + 0x7fff + ((x.u >> 16) & 1);   // RNE
    return (unsigned short)(r >> 16);
}
__device__ __forceinline__ float b2f(unsigned short u) {
    union { unsigned u; float f; } x; x.u = ((unsigned)u) << 16;
    return x.f;
}

#define GLD_LDS16(g, l)                                                        \
    __builtin_amdgcn_global_load_lds(                                          \
        (const __attribute__((address_space(1))) void*)(g),                    \
        (__attribute__((address_space(3))) void*)(l), 16, 0, 0)

// ---------------------------------------------------------------------------
// aggr[v] = h[v] + emb1[0] + emb2[0]   (self-loop, zero edge_attr). fp32 h.
// ---------------------------------------------------------------------------
__global__ __launch_bounds__(256) void k_init_f32(
    const float* __restrict__ h, const float* __restrict__ emb1,
    const float* __restrict__ emb2, float* __restrict__ A, int n)
{
    int idx = blockIdx.x * blockDim.x + threadIdx.x;
    if (idx >= n * F4) return;
    int v = idx / F4, c = idx % F4;
    float4 hv = ((const float4*)h)[v * F4 + c];
    float4 e1 = ((const float4*)emb1)[c];
    float4 e2 = ((const float4*)emb2)[c];
    float4 r;
    r.x = hv.x + e1.x + e2.x;  r.y = hv.y + e1.y + e2.y;
    r.z = hv.z + e1.z + e2.z;  r.w = hv.w + e1.w + e2.w;
    ((float4*)A)[v * F4 + c] = r;
}

// bf16 h variant
__global__ __launch_bounds__(256) void k_init_b16(
    const unsigned short* __restrict__ h, const float* __restrict__ emb1,
    const float* __restrict__ emb2, float* __restrict__ A, int n)
{
    int idx = blockIdx.x * blockDim.x + threadIdx.x;
    if (idx >= n * F4) return;
    int v = idx / F4, c = idx % F4;
    ushort4 hv = ((const ushort4*)h)[v * F4 + c];
    float4 e1 = ((const float4*)emb1)[c];
    float4 e2 = ((const float4*)emb2)[c];
    float4 r;
    r.x = b2f(hv.x) + e1.x + e2.x;  r.y = b2f(hv.y) + e1.y + e2.y;
    r.z = b2f(hv.z) + e1.z + e2.z;  r.w = b2f(hv.w) + e1.w + e2.w;
    ((float4*)A)[v * F4 + c] = r;
}

// ---------------------------------------------------------------------------
// edge scatter: aggr[dst[e]] += h[src[e]] + emb1[type] + emb2[dir]
// ---------------------------------------------------------------------------
__global__ __launch_bounds__(256) void k_scat_f32(
    const float* __restrict__ h, const int* __restrict__ ei,
    const int* __restrict__ ea, const float* __restrict__ emb1,
    const float* __restrict__ emb2, float* __restrict__ A, int E)
{
    int idx = blockIdx.x * blockDim.x + threadIdx.x;
    if (idx >= E * F4) return;
    int e = idx / F4, c = idx % F4;
    int s = ei[e], v = ei[E + e];
    int t = ea[2 * e], d = ea[2 * e + 1];
    float4 hv = ((const float4*)h)[s * F4 + c];
    float4 e1 = ((const float4*)emb1)[t * F4 + c];
    float4 e2 = ((const float4*)emb2)[d * F4 + c];
    float m0 = hv.x + e1.x + e2.x, m1 = hv.y + e1.y + e2.y;
    float m2 = hv.z + e1.z + e2.z, m3 = hv.w + e1.w + e2.w;
    float* p = A + (size_t)v * NFEAT + 4 * c;
    __hip_atomic_fetch_add(p + 0, m0, __ATOMIC_RELAXED, __HIP_MEMORY_SCOPE_AGENT);
    __hip_atomic_fetch_add(p + 1, m1, __ATOMIC_RELAXED, __HIP_MEMORY_SCOPE_AGENT);
    __hip_atomic_fetch_add(p + 2, m2, __ATOMIC_RELAXED, __HIP_MEMORY_SCOPE_AGENT);
    __hip_atomic_fetch_add(p + 3, m3, __ATOMIC_RELAXED, __HIP_MEMORY_SCOPE_AGENT);
}

__global__ __launch_bounds__(256) void k_scat_b16(
    const unsigned short* __restrict__ h, const int* __restrict__ ei,
    const int* __restrict__ ea, const float* __restrict__ emb1,
    const float* __restrict__ emb2, float* __restrict__ A, int E)
{
    int idx = blockIdx.x * blockDim.x + threadIdx.x;
    if (idx >= E * F4) return;
    int e = idx / F4, c = idx % F4;
    int s = ei[e], v = ei[E + e];
    int t = ea[2 * e], d = ea[2 * e + 1];
    ushort4 hv = ((const ushort4*)h)[s * F4 + c];
    float4 e1 = ((const float4*)emb1)[t * F4 + c];
    float4 e2 = ((const float4*)emb2)[d * F4 + c];
    float m0 = b2f(hv.x) + e1.x + e2.x, m1 = b2f(hv.y) + e1.y + e2.y;
    float m2 = b2f(hv.z) + e1.z + e2.z, m3 = b2f(hv.w) + e1.w + e2.w;
    float* p = A + (size_t)v * NFEAT + 4 * c;
    __hip_atomic_fetch_add(p + 0, m0, __ATOMIC_RELAXED, __HIP_MEMORY_SCOPE_AGENT);
    __hip_atomic_fetch_add(p + 1, m1, __ATOMIC_RELAXED, __HIP_MEMORY_SCOPE_AGENT);
    __hip_atomic_fetch_add(p + 2, m2, __ATOMIC_RELAXED, __HIP_MEMORY_SCOPE_AGENT);
    __hip_atomic_fetch_add(p + 3, m3, __ATOMIC_RELAXED, __HIP_MEMORY_SCOPE_AGENT);
}

// ---------------------------------------------------------------------------
// A fp32 [n x 300] -> Ab bf16 [Mpad x 320], zero pad (cols 300.. and rows n..)
// one thread per 8 output cols (16B store)
// ---------------------------------------------------------------------------
__global__ __launch_bounds__(256) void k_cvtA(
    const float* __restrict__ A, unsigned short* __restrict__ Ab, int n, int Mpad)
{
    int t = blockIdx.x * blockDim.x + threadIdx.x;
    int total = Mpad * (K1P / 8);
    if (t >= total) return;
    int row = t / (K1P / 8), c8 = t % (K1P / 8);
    int col0 = c8 * 8;
    unsigned short o[8];
#pragma unroll
    for (int j = 0; j < 8; ++j) {
        int col = col0 + j;
        float v = (row < n && col < NFEAT) ? A[(size_t)row * NFEAT + col] : 0.f;
        o[j] = f2b(v);
    }
    *(uint4*)&Ab[(size_t)row * K1P + col0] = *(uint4*)o;
}

// ---------------------------------------------------------------------------
// Wt[n*Kpad + k] = bf16(W[k*cols + n]) if k<rows && n<cols else 0
// ---------------------------------------------------------------------------
__global__ __launch_bounds__(256) void k_cvtW(
    const float* __restrict__ W, unsigned short* __restrict__ Wt,
    int rows, int cols, int Kpad, int Npad)
{
    int t = blockIdx.x * blockDim.x + threadIdx.x;
    if (t >= Npad * Kpad) return;
    int nn = t / Kpad, k = t % Kpad;
    float v = (k < rows && nn < cols) ? W[(size_t)k * cols + nn] : 0.f;
    Wt[t] = f2b(v);
}

// ---------------------------------------------------------------------------
// bf16 MFMA GEMM: C = relu(A @ B + bias), A [M x K] row-major bf16,
// B given transposed Bt [N x K] row-major bf16. 128x128 tile, BK=32,
// 256 threads = 4 waves in 2x2, each wave 64x64 (4x4 of 16x16x32 MFMA).
// ---------------------------------------------------------------------------
__global__ __launch_bounds__(256) void k_gemm(
    const unsigned short* __restrict__ Ag, const unsigned short* __restrict__ Bg,
    const float* __restrict__ bias, int bias_n,
    unsigned short* __restrict__ C, int ldc, int store_rows, int store_cols,
    int K)
{
    __shared__ unsigned short sA[128 * 32];   // 8 KB
    __shared__ unsigned short sB[128 * 32];   // 8 KB

    int tid  = threadIdx.x;
    int wave = tid >> 6, lane = tid & 63;
    int m0 = blockIdx.y * 128, n0 = blockIdx.x * 128;
    int wm = (wave >> 1) * 64, wn = (wave & 1) * 64;

    f32x4 acc[4][4];
#pragma unroll
    for (int i = 0; i < 4; ++i)
#pragma unroll
        for (int j = 0; j < 4; ++j)
            acc[i][j] = (f32x4){0.f, 0.f, 0.f, 0.f};

    const unsigned short* Abase = Ag + (size_t)m0 * K;
    const unsigned short* Bbase = Bg + (size_t)n0 * K;

    int row_l = tid >> 2;          // 0..63  (issue 1 adds +64)
    int k8    = (tid & 3) * 8;     // 0,8,16,24

    int mrow = lane & 15;
    int kq   = (lane >> 4) * 8;

    for (int k0 = 0; k0 < K; k0 += 32) {
        GLD_LDS16(Abase + (size_t)row_l * K + k0 + k8,        &sA[tid * 8]);
        GLD_LDS16(Abase + (size_t)(row_l + 64) * K + k0 + k8, &sA[(256 + tid) * 8]);
        GLD_LDS16(Bbase + (size_t)row_l * K + k0 + k8,        &sB[tid * 8]);
        GLD_LDS16(Bbase + (size_t)(row_l + 64) * K + k0 + k8, &sB[(256 + tid) * 8]);
        __syncthreads();

        bf16x8 af[4], bf[4];
#pragma unroll
        for (int i = 0; i < 4; ++i) {
            af[i] = *(const bf16x8*)&sA[(wm + i * 16 + mrow) * 32 + kq];
            bf[i] = *(const bf16x8*)&sB[(wn + i * 16 + mrow) * 32 + kq];
        }
#pragma unroll
        for (int i = 0; i < 4; ++i)
#pragma unroll
            for (int j = 0; j < 4; ++j)
                acc[i][j] = __builtin_amdgcn_mfma_f32_16x16x32_bf16(
                    af[i], bf[j], acc[i][j], 0, 0, 0);
        __syncthreads();
    }

    // epilogue: C/D layout col = lane&15, row = (lane>>4)*4 + reg
    int colq = lane & 15, rq = (lane >> 4) * 4;
#pragma unroll
    for (int j = 0; j < 4; ++j) {
        int col = n0 + wn + j * 16 + colq;
        if (col >= store_cols) continue;
        float bv = (col < bias_n) ? bias[col] : 0.f;
#pragma unroll
        for (int i = 0; i < 4; ++i) {
            int rbase = m0 + wm + i * 16 + rq;
#pragma unroll
            for (int r = 0; r < 4; ++r) {
                int row = rbase + r;
                if (row < store_rows) {
                    float v = acc[i][j][r] + bv;
                    v = fmaxf(v, 0.f);
                    C[(size_t)row * ldc + col] = f2b(v);
                }
            }
        }
    }
}

// ---------------------------------------------------------------------------
// pool: g[gid] = sum over rows with batch==gid (sorted -> binary search). H bf16.
// ---------------------------------------------------------------------------
__global__ __launch_bounds__(256) void k_pool(
    const unsigned short* __restrict__ H, const int* __restrict__ batch,
    float* __restrict__ g, int n)
{
    int gid = blockIdx.x;
    int lo = 0, hi = n;
    while (lo < hi) { int mid = (lo + hi) >> 1; if (batch[mid] < gid) lo = mid + 1; else hi = mid; }
    int start = lo;
    hi = n;
    while (lo < hi) { int mid = (lo + hi) >> 1; if (batch[mid] < gid + 1) lo = mid + 1; else hi = mid; }
    int end = lo;

    for (int f = threadIdx.x; f < NFEAT; f += blockDim.x) {
        float acc = 0.f;
        for (int v = start; v < end; ++v) acc += b2f(H[(size_t)v * NFEAT + f]);
        g[(size_t)gid * NFEAT + f] = acc;
    }
}

// ---------------------------------------------------------------------------
// out = g @ Wfc + bfc   (2048x300 @ 300x300), fp32
// ---------------------------------------------------------------------------
__global__ __launch_bounds__(256) void k_final(
    const float* __restrict__ g, const float* __restrict__ Wfc,
    const float* __restrict__ bfc, float* __restrict__ out)
{
    int idx = blockIdx.x * blockDim.x + threadIdx.x;
    if (idx >= NGRAPH * NFEAT) return;
    int r = idx / NFEAT, c = idx % NFEAT;
    float acc = bfc[c];
    for (int k = 0; k < NFEAT; ++k)
        acc = fmaf(g[(size_t)r * NFEAT + k], Wfc[(size_t)k * NFEAT + c], acc);
    out[idx] = acc;
}

extern "C" void kernel_launch(void* const* d_in, const int* in_sizes, int n_in,
                              void* d_out, int out_size, void* d_ws, size_t ws_size,
                              hipStream_t stream)
{
    const float* x    = (const float*)d_in[0];
    const int*   ei   = (const int*)  d_in[1];
    const int*   ea   = (const int*)  d_in[2];
    const int*   batch= (const int*)  d_in[3];
    const float* emb1 = (const float*)d_in[4];
    const float* emb2 = (const float*)d_in[5];
    const float* W1   = (const float*)d_in[6];
    const float* b1   = (const float*)d_in[7];
    const float* W2   = (const float*)d_in[8];
    const float* b2   = (const float*)d_in[9];
    const float* Wfc  = (const float*)d_in[10];
    const float* bfc  = (const float*)d_in[11];
    float* out = (float*)d_out;

    int n = in_sizes[0] / NFEAT;   // 100000
    int E = in_sizes[1] / 2;       // 200000
    int MT   = (n + 127) / 128;    // 782
    int Mpad = MT * 128;           // 100096

    // workspace layout (bytes):
    // R1: A fp32 [n x 300] (120.0 MB), later T bf16 [Mpad x 640] (128.12 MB)
    // R2: Ab bf16 [Mpad x 320]  (64.06 MB)
    // R3: H  bf16 [n x 300]     (60.0 MB)
    // R4: Wt1 [640x320] bf16, Wt2 [384x640] bf16, g fp32 [2048x300]
    char* wsb = (char*)d_ws;
    size_t szR1 = (size_t)Mpad * N1P * 2;          // 128,122,880
    size_t szR2 = (size_t)Mpad * K1P * 2;          //  64,061,440
    size_t szR3 = (size_t)n * NFEAT * 2;           //  60,000,000
    float*          A   = (float*)wsb;             // R1 as fp32 aggr
    unsigned short* T   = (unsigned short*)wsb;    // R1 as bf16 T
    unsigned short* Ab  = (unsigned short*)(wsb + szR1);
    unsigned short* Hb  = (unsigned short*)(wsb + szR1 + szR2);
    unsigned short* Wt1 = (unsigned short*)(wsb + szR1 + szR2 + szR3);
    unsigned short* Wt2 = Wt1 + (size_t)N1P * K1P;
    float*          g   = (float*)(Wt2 + (size_t)N2P * K2P);

    dim3 blk(256);
    int initBlocks = (n * F4 + 255) / 256;
    int scatBlocks = (E * F4 + 255) / 256;
    int cvtABlocks = (Mpad * (K1P / 8) + 255) / 256;

    // weights -> transposed padded bf16 (cheap, every call: ws is re-poisoned)
    k_cvtW<<<(N1P * K1P + 255) / 256, blk, 0, stream>>>(W1, Wt1, NFEAT, 600, K1P, N1P);
    k_cvtW<<<(N2P * K2P + 255) / 256, blk, 0, stream>>>(W2, Wt2, 600, NFEAT, K2P, N2P);

    // ---- layer 1 ----
    k_init_f32<<<initBlocks, blk, 0, stream>>>(x, emb1, emb2, A, n);
    k_scat_f32<<<scatBlocks, blk, 0, stream>>>(x, ei, ea, emb1, emb2, A, E);
    k_cvtA    <<<cvtABlocks, blk, 0, stream>>>(A, Ab, n, Mpad);
    k_gemm<<<dim3(N1P / 128, MT), blk, 0, stream>>>(Ab, Wt1, b1, 600, T, N1P, Mpad, N1P, K1P);
    k_gemm<<<dim3(N2P / 128, MT), blk, 0, stream>>>(T, Wt2, b2, NFEAT, Hb, NFEAT, n, NFEAT, K2P);

    // ---- layer 2 ----
    k_init_b16<<<initBlocks, blk, 0, stream>>>(Hb, emb1, emb2, A, n);
    k_scat_b16<<<scatBlocks, blk, 0, stream>>>(Hb, ei, ea, emb1, emb2, A, E);
    k_cvtA    <<<cvtABlocks, blk, 0, stream>>>(A, Ab, n, Mpad);
    k_gemm<<<dim3(N1P / 128, MT), blk, 0, stream>>>(Ab, Wt1, b1, 600, T, N1P, Mpad, N1P, K1P);
    k_gemm<<<dim3(N2P / 128, MT), blk, 0, stream>>>(T, Wt2, b2, NFEAT, Hb, NFEAT, n, NFEAT, K2P);

    // ---- pool + final ----
    k_pool <<<NGRAPH, blk, 0, stream>>>(Hb, batch, g, n);
    k_final<<<(NGRAPH * NFEAT + 255) / 256, blk, 0, stream>>>(g, Wfc, bfc, out);
}

// Round 3
// 925.856 us; speedup vs baseline: 10.0135x; 2.8688x over previous
//
#include <hip/hip_runtime.h>
#include <hip/hip_bf16.h>

#define NFEAT 300
#define KP 320           // padded feature stride (bf16 rows)
#define NGRAPH 2048
#define N1P 640          // padded N for GEMM1 (600 -> 640)
#define N2P 384          // padded N for GEMM2 (300 -> 384)
#define NTD 18           // bond_type(6) * bond_dir(3)
#define SCAN_B 2048      // elements per scan block (256 thr * 8)

typedef __bf16 bf16x8 __attribute__((ext_vector_type(8)));
typedef float  f32x4  __attribute__((ext_vector_type(4)));
typedef unsigned short u16x8 __attribute__((ext_vector_type(8)));

__device__ __forceinline__ unsigned short f2b(float v) {
    union { float f; unsigned u; } x; x.f = v;
    unsigned r = x.u + 0x7fff + ((x.u >> 16) & 1);   // RNE
    return (unsigned short)(r >> 16);
}
__device__ __forceinline__ float b2f(unsigned short u) {
    union { unsigned u; float f; } x; x.u = ((unsigned)u) << 16;
    return x.f;
}

#define GLD_LDS16(g, l)                                                        \
    __builtin_amdgcn_global_load_lds(                                          \
        (const __attribute__((address_space(1))) void*)(g),                    \
        (__attribute__((address_space(3))) void*)(l), 16, 0, 0)

// ---------------------------------------------------------------------------
// embc[td][c] = emb1[td/3][c] + emb2[td%3][c]  (fp32, [18 x 320], pad cols 0)
// td = t*3 + d; self-loop term is embc[0] (attr fill = (0,0)).
// ---------------------------------------------------------------------------
__global__ __launch_bounds__(256) void k_embc(
    const float* __restrict__ emb1, const float* __restrict__ emb2,
    float* __restrict__ embc)
{
    int t = blockIdx.x * blockDim.x + threadIdx.x;
    if (t >= NTD * KP) return;
    int td = t / KP, c = t % KP;
    int t1 = td / 3, d = td % 3;
    embc[t] = (c < NFEAT) ? emb1[t1 * NFEAT + c] + emb2[d * NFEAT + c] : 0.f;
}

// ---------------------------------------------------------------------------
// x fp32 [n x 300] -> xb bf16 [Mpad x 320] (pads zero)
// ---------------------------------------------------------------------------
__global__ __launch_bounds__(256) void k_cvtX(
    const float* __restrict__ x, unsigned short* __restrict__ xb, int n, int Mpad)
{
    int idx = blockIdx.x * blockDim.x + threadIdx.x;
    if (idx >= Mpad * (KP / 8)) return;
    int row = idx / (KP / 8), c0 = (idx % (KP / 8)) * 8;
    unsigned short o[8];
#pragma unroll
    for (int j = 0; j < 8; ++j) {
        int col = c0 + j;
        float v = (row < n && col < NFEAT) ? x[(size_t)row * NFEAT + col] : 0.f;
        o[j] = f2b(v);
    }
    *(uint4*)&xb[(size_t)row * KP + c0] = *(uint4*)o;
}

// ---------------------------------------------------------------------------
// CSR build: deg -> exclusive-scan offsets -> cursor fill with packed records
// ---------------------------------------------------------------------------
__global__ __launch_bounds__(256) void k_zero(int* __restrict__ p, int n)
{
    int i = blockIdx.x * blockDim.x + threadIdx.x;
    if (i < n) p[i] = 0;
}

__global__ __launch_bounds__(256) void k_deg(
    const int* __restrict__ ei, int* __restrict__ deg, int E)
{
    int e = blockIdx.x * blockDim.x + threadIdx.x;
    if (e >= E) return;
    atomicAdd(&deg[ei[E + e]], 1);
}

// phase 1: per-block inclusive scan of deg into offsets[i+1]; block sums out
__global__ __launch_bounds__(256) void k_scan1(
    const int* __restrict__ deg, int* __restrict__ offsets,
    int* __restrict__ bsum, int n)
{
    __shared__ int sh[256];
    int tid = threadIdx.x;
    int base = blockIdx.x * SCAN_B + tid * 8;
    int v[8], run = 0;
#pragma unroll
    for (int j = 0; j < 8; ++j) {
        int i = base + j;
        v[j] = (i < n) ? deg[i] : 0;
        run += v[j];
        v[j] = run;                 // inclusive within thread
    }
    sh[tid] = run;
    __syncthreads();
    for (int off = 1; off < 256; off <<= 1) {
        int t = (tid >= off) ? sh[tid - off] : 0;
        __syncthreads();
        sh[tid] += t;
        __syncthreads();
    }
    int excl = sh[tid] - run;
#pragma unroll
    for (int j = 0; j < 8; ++j) {
        int i = base + j;
        if (i < n) offsets[i + 1] = excl + v[j];
    }
    if (tid == 0) bsum[blockIdx.x] = sh[255];
}

// phase 2: serial exclusive scan of block sums (tiny)
__global__ void k_scan2(int* __restrict__ bsum, int nb, int* __restrict__ offsets)
{
    if (threadIdx.x == 0 && blockIdx.x == 0) {
        int run = 0;
        for (int b = 0; b < nb; ++b) { int t = bsum[b]; bsum[b] = run; run += t; }
        offsets[0] = 0;
    }
}

// phase 3: finalize offsets, derive cursor (= exclusive prefix)
__global__ __launch_bounds__(256) void k_scan3(
    const int* __restrict__ deg, int* __restrict__ offsets,
    const int* __restrict__ bsum, int* __restrict__ cursor, int n)
{
    int i = blockIdx.x * blockDim.x + threadIdx.x;
    if (i >= n) return;
    int fin = offsets[i + 1] + bsum[i / SCAN_B];
    offsets[i + 1] = fin;
    cursor[i] = fin - deg[i];
}

__global__ __launch_bounds__(256) void k_fill(
    const int* __restrict__ ei, const int* __restrict__ ea,
    int* __restrict__ cursor, int* __restrict__ edgerec, int E)
{
    int e = blockIdx.x * blockDim.x + threadIdx.x;
    if (e >= E) return;
    int dst = ei[E + e];
    int pos = atomicAdd(&cursor[dst], 1);
    int src = ei[e];
    int td  = ea[2 * e] * 3 + ea[2 * e + 1];
    edgerec[pos] = src | (td << 20);
}

// ---------------------------------------------------------------------------
// Gather-side aggregation:
// Ab[v] = bf16( h[v] + embc[0] + sum_{e: dst=v} ( h[src_e] + embc[td_e] ) )
// one thread per (node, 8-col chunk); rows >= n zero-filled.
// ---------------------------------------------------------------------------
__global__ __launch_bounds__(256) void k_aggr(
    const unsigned short* __restrict__ h,    // [Mpad x 320] bf16
    const int* __restrict__ offsets, const int* __restrict__ edgerec,
    const float* __restrict__ embc,          // [18 x 320] fp32
    unsigned short* __restrict__ Ab, int n, int Mpad)
{
    int idx = blockIdx.x * blockDim.x + threadIdx.x;
    if (idx >= Mpad * (KP / 8)) return;
    int v = idx / (KP / 8), c0 = (idx % (KP / 8)) * 8;
    unsigned short* outp = &Ab[(size_t)v * KP + c0];
    if (v >= n) {
        *(uint4*)outp = make_uint4(0, 0, 0, 0);
        return;
    }
    float acc[8];
    u16x8 hv = *(const u16x8*)&h[(size_t)v * KP + c0];
    const float* e0 = embc + c0;
#pragma unroll
    for (int j = 0; j < 8; ++j) acc[j] = b2f(hv[j]) + e0[j];

    int beg = offsets[v], end = offsets[v + 1];
    for (int e = beg; e < end; ++e) {
        int rec = edgerec[e];
        int src = rec & 0xFFFFF;
        int td  = rec >> 20;
        u16x8 hs = *(const u16x8*)&h[(size_t)src * KP + c0];
        const float* ee = embc + td * KP + c0;
#pragma unroll
        for (int j = 0; j < 8; ++j) acc[j] += b2f(hs[j]) + ee[j];
    }
    unsigned short o[8];
#pragma unroll
    for (int j = 0; j < 8; ++j) o[j] = f2b(acc[j]);
    *(uint4*)outp = *(uint4*)o;
}

// ---------------------------------------------------------------------------
// Wt[n*Kpad + k] = bf16(W[k*cols + n]) if in range else 0
// ---------------------------------------------------------------------------
__global__ __launch_bounds__(256) void k_cvtW(
    const float* __restrict__ W, unsigned short* __restrict__ Wt,
    int rows, int cols, int Kpad, int Npad)
{
    int t = blockIdx.x * blockDim.x + threadIdx.x;
    if (t >= Npad * Kpad) return;
    int nn = t / Kpad, k = t % Kpad;
    float v = (k < rows && nn < cols) ? W[(size_t)k * cols + nn] : 0.f;
    Wt[t] = f2b(v);
}

// ---------------------------------------------------------------------------
// bf16 MFMA GEMM: C = relu(A @ B + bias). A [M x K] rm bf16, Bt [N x K] rm.
// 128x128 tile, BK=32, 4 waves 2x2, each wave 64x64 of 16x16x32 MFMA.
// ---------------------------------------------------------------------------
__global__ __launch_bounds__(256) void k_gemm(
    const unsigned short* __restrict__ Ag, const unsigned short* __restrict__ Bg,
    const float* __restrict__ bias, int bias_n,
    unsigned short* __restrict__ C, int ldc, int store_rows, int store_cols,
    int K)
{
    __shared__ unsigned short sA[128 * 32];
    __shared__ unsigned short sB[128 * 32];

    int tid  = threadIdx.x;
    int wave = tid >> 6, lane = tid & 63;
    int m0 = blockIdx.y * 128, n0 = blockIdx.x * 128;
    int wm = (wave >> 1) * 64, wn = (wave & 1) * 64;

    f32x4 acc[4][4];
#pragma unroll
    for (int i = 0; i < 4; ++i)
#pragma unroll
        for (int j = 0; j < 4; ++j)
            acc[i][j] = (f32x4){0.f, 0.f, 0.f, 0.f};

    const unsigned short* Abase = Ag + (size_t)m0 * K;
    const unsigned short* Bbase = Bg + (size_t)n0 * K;

    int row_l = tid >> 2;
    int k8    = (tid & 3) * 8;
    int mrow  = lane & 15;
    int kq    = (lane >> 4) * 8;

    for (int k0 = 0; k0 < K; k0 += 32) {
        GLD_LDS16(Abase + (size_t)row_l * K + k0 + k8,        &sA[tid * 8]);
        GLD_LDS16(Abase + (size_t)(row_l + 64) * K + k0 + k8, &sA[(256 + tid) * 8]);
        GLD_LDS16(Bbase + (size_t)row_l * K + k0 + k8,        &sB[tid * 8]);
        GLD_LDS16(Bbase + (size_t)(row_l + 64) * K + k0 + k8, &sB[(256 + tid) * 8]);
        __syncthreads();

        bf16x8 af[4], bfv[4];
#pragma unroll
        for (int i = 0; i < 4; ++i) {
            af[i]  = *(const bf16x8*)&sA[(wm + i * 16 + mrow) * 32 + kq];
            bfv[i] = *(const bf16x8*)&sB[(wn + i * 16 + mrow) * 32 + kq];
        }
#pragma unroll
        for (int i = 0; i < 4; ++i)
#pragma unroll
            for (int j = 0; j < 4; ++j)
                acc[i][j] = __builtin_amdgcn_mfma_f32_16x16x32_bf16(
                    af[i], bfv[j], acc[i][j], 0, 0, 0);
        __syncthreads();
    }

    int colq = lane & 15, rq = (lane >> 4) * 4;
#pragma unroll
    for (int j = 0; j < 4; ++j) {
        int col = n0 + wn + j * 16 + colq;
        if (col >= store_cols) continue;
        float bv = (col < bias_n) ? bias[col] : 0.f;
#pragma unroll
        for (int i = 0; i < 4; ++i) {
            int rbase = m0 + wm + i * 16 + rq;
#pragma unroll
            for (int r = 0; r < 4; ++r) {
                int row = rbase + r;
                if (row < store_rows) {
                    float v = fmaxf(acc[i][j][r] + bv, 0.f);
                    C[(size_t)row * ldc + col] = f2b(v);
                }
            }
        }
    }
}

// ---------------------------------------------------------------------------
// pool: g[gid] = sum of Hb rows (bf16, stride KP) with batch==gid (sorted)
// ---------------------------------------------------------------------------
__global__ __launch_bounds__(256) void k_pool(
    const unsigned short* __restrict__ H, const int* __restrict__ batch,
    float* __restrict__ g, int n)
{
    int gid = blockIdx.x;
    int lo = 0, hi = n;
    while (lo < hi) { int mid = (lo + hi) >> 1; if (batch[mid] < gid) lo = mid + 1; else hi = mid; }
    int start = lo;
    hi = n;
    while (lo < hi) { int mid = (lo + hi) >> 1; if (batch[mid] < gid + 1) lo = mid + 1; else hi = mid; }
    int end = lo;

    for (int f = threadIdx.x; f < NFEAT; f += blockDim.x) {
        float acc = 0.f;
        for (int v = start; v < end; ++v) acc += b2f(H[(size_t)v * KP + f]);
        g[(size_t)gid * NFEAT + f] = acc;
    }
}

// ---------------------------------------------------------------------------
// out = g @ Wfc + bfc   (2048x300 @ 300x300), fp32
// ---------------------------------------------------------------------------
__global__ __launch_bounds__(256) void k_final(
    const float* __restrict__ g, const float* __restrict__ Wfc,
    const float* __restrict__ bfc, float* __restrict__ out)
{
    int idx = blockIdx.x * blockDim.x + threadIdx.x;
    if (idx >= NGRAPH * NFEAT) return;
    int r = idx / NFEAT, c = idx % NFEAT;
    float acc = bfc[c];
    for (int k = 0; k < NFEAT; ++k)
        acc = fmaf(g[(size_t)r * NFEAT + k], Wfc[(size_t)k * NFEAT + c], acc);
    out[idx] = acc;
}

extern "C" void kernel_launch(void* const* d_in, const int* in_sizes, int n_in,
                              void* d_out, int out_size, void* d_ws, size_t ws_size,
                              hipStream_t stream)
{
    const float* x    = (const float*)d_in[0];
    const int*   ei   = (const int*)  d_in[1];
    const int*   ea   = (const int*)  d_in[2];
    const int*   batch= (const int*)  d_in[3];
    const float* emb1 = (const float*)d_in[4];
    const float* emb2 = (const float*)d_in[5];
    const float* W1   = (const float*)d_in[6];
    const float* b1   = (const float*)d_in[7];
    const float* W2   = (const float*)d_in[8];
    const float* b2   = (const float*)d_in[9];
    const float* Wfc  = (const float*)d_in[10];
    const float* bfc  = (const float*)d_in[11];
    float* out = (float*)d_out;

    int n = in_sizes[0] / NFEAT;   // 100000
    int E = in_sizes[1] / 2;       // 200000
    int MT   = (n + 127) / 128;    // 782
    int Mpad = MT * 128;           // 100096

    // ---- workspace layout ----
    char* p = (char*)d_ws;
    auto take = [&](size_t bytes) { char* r = p; p += (bytes + 255) & ~(size_t)255; return r; };
    unsigned short* T    = (unsigned short*)take((size_t)Mpad * N1P * 2); // 128.1 MB
    unsigned short* xb   = T;                                             // overlay: dead before T written
    unsigned short* Ab   = (unsigned short*)take((size_t)Mpad * KP * 2);  // 64.06 MB
    unsigned short* Hb   = (unsigned short*)take((size_t)Mpad * KP * 2);  // 64.06 MB
    unsigned short* Wt1  = (unsigned short*)take((size_t)N1P * KP * 2);
    unsigned short* Wt2  = (unsigned short*)take((size_t)N2P * N1P * 2);
    float*          embc = (float*)take((size_t)NTD * KP * 4);
    float*          g    = (float*)take((size_t)NGRAPH * NFEAT * 4);
    int*            deg  = (int*)take((size_t)n * 4);
    int*            offs = (int*)take((size_t)(n + 1) * 4);
    int*            curs = (int*)take((size_t)n * 4);
    int*            erec = (int*)take((size_t)E * 4);
    int*            bsum = (int*)take(256 * 4);

    dim3 blk(256);
    int chunkThreads = Mpad * (KP / 8);
    int chunkBlocks  = (chunkThreads + 255) / 256;
    int nb = (n + SCAN_B - 1) / SCAN_B;

    // ---- one-time prep (per call) ----
    k_cvtW<<<(N1P * KP + 255) / 256, blk, 0, stream>>>(W1, Wt1, NFEAT, 600, KP, N1P);
    k_cvtW<<<(N2P * N1P + 255) / 256, blk, 0, stream>>>(W2, Wt2, 600, NFEAT, N1P, N2P);
    k_embc<<<(NTD * KP + 255) / 256, blk, 0, stream>>>(emb1, emb2, embc);
    k_cvtX<<<chunkBlocks, blk, 0, stream>>>(x, xb, n, Mpad);

    // ---- CSR build (dst-sorted edge records) ----
    k_zero <<<(n + 255) / 256, blk, 0, stream>>>(deg, n);
    k_deg  <<<(E + 255) / 256, blk, 0, stream>>>(ei, deg, E);
    k_scan1<<<nb, blk, 0, stream>>>(deg, offs, bsum, n);
    k_scan2<<<1, 64, 0, stream>>>(bsum, nb, offs);
    k_scan3<<<(n + 255) / 256, blk, 0, stream>>>(deg, offs, bsum, curs, n);
    k_fill <<<(E + 255) / 256, blk, 0, stream>>>(ei, ea, curs, erec, E);

    // ---- layer 1 ----
    k_aggr<<<chunkBlocks, blk, 0, stream>>>(xb, offs, erec, embc, Ab, n, Mpad);
    k_gemm<<<dim3(N1P / 128, MT), blk, 0, stream>>>(Ab, Wt1, b1, 600, T, N1P, Mpad, N1P, KP);
    k_gemm<<<dim3(N2P / 128, MT), blk, 0, stream>>>(T, Wt2, b2, NFEAT, Hb, KP, Mpad, KP, N1P);

    // ---- layer 2 ----
    k_aggr<<<chunkBlocks, blk, 0, stream>>>(Hb, offs, erec, embc, Ab, n, Mpad);
    k_gemm<<<dim3(N1P / 128, MT), blk, 0, stream>>>(Ab, Wt1, b1, 600, T, N1P, Mpad, N1P, KP);
    k_gemm<<<dim3(N2P / 128, MT), blk, 0, stream>>>(T, Wt2, b2, NFEAT, Hb, KP, Mpad, KP, N1P);

    // ---- pool + final ----
    k_pool <<<NGRAPH, blk, 0, stream>>>(Hb, batch, g, n);
    k_final<<<(NGRAPH * NFEAT + 255) / 256, blk, 0, stream>>>(g, Wfc, bfc, out);
}